// Round 1
// baseline (381.015 us; speedup 1.0000x reference)
//
#include <hip/hip_runtime.h>
#include <stdint.h>

// TrellisQuantizer: out[i,j,:] = tlut[(h>>5)&1023] ^ sign(h bits 15/13), h=(e+1)*e
// Memory-bound: 134 MB read (encoded int32) + 268 MB write (fp32 out)
// -> ~64 us floor at 6.3 TB/s measured-achievable.
//
// v2 changes vs prior best (358 us harness):
//  * Split-channel LDS LUT (sx/sy float arrays). float2[1024] put entry e at
//    bank (2e)%32 -> random gathers hit only 16 even bank-pairs (~4-8-way
//    conflicts, ~3x on every ds_read_b64). Split arrays put entry e at bank
//    e%32 -> all 32 banks, avg 2-way = free (m136).
//  * 16 B/lane loads (uint4 = 4 codes) -- coalescing sweet spot, half the
//    VMEM load instructions.
//  * Grid 2048 = exact resident-block capacity (256 CU x 8 blocks/CU);
//    LUT staged 4x fewer times, 16 iters/thread amortizes setup.

constexpr int TLUT_ENTRIES = 1024;   // 2^10 entries (8 KiB, LDS-resident)
constexpr int BLOCK = 256;
constexpr int GRID  = 2048;

typedef float    f32x4 __attribute__((ext_vector_type(4)));
typedef uint32_t u32x4 __attribute__((ext_vector_type(4)));

__global__ __launch_bounds__(BLOCK) void trellis_dequant_kernel(
    const float2* __restrict__ tlut,   // [1024] float2
    const u32x4*  __restrict__ enc,    // encoded viewed as packed quads of int32
    f32x4*        __restrict__ out,    // 2x float4 per input quad
    int n4)                            // number of uint4 (code-quad) elements
{
    // Split channels so random gathers spread across all 32 LDS banks.
    __shared__ float sx[TLUT_ENTRIES];
    __shared__ float sy[TLUT_ENTRIES];
    for (int j = threadIdx.x; j < TLUT_ENTRIES; j += BLOCK) {
        float2 t = tlut[j];
        sx[j] = t.x;
        sy[j] = t.y;
    }
    __syncthreads();

    const int stride = GRID * BLOCK;
    int i = blockIdx.x * BLOCK + threadIdx.x;
    #pragma unroll 2
    for (; i < n4; i += stride) {
        // Streamed once, never re-read -> nontemporal, don't occupy L2.
        u32x4 e4 = __builtin_nontemporal_load(&enc[i]);

        uint32_t h0 = (e4.x + 1u) * e4.x;
        uint32_t h1 = (e4.y + 1u) * e4.y;
        uint32_t h2 = (e4.z + 1u) * e4.z;
        uint32_t h3 = (e4.w + 1u) * e4.w;

        uint32_t i0 = (h0 >> 5) & 1023u;
        uint32_t i1 = (h1 >> 5) & 1023u;
        uint32_t i2 = (h2 >> 5) & 1023u;
        uint32_t i3 = (h3 >> 5) & 1023u;

        float x0 = sx[i0], y0 = sy[i0];
        float x1 = sx[i1], y1 = sy[i1];
        float x2 = sx[i2], y2 = sy[i2];
        float x3 = sx[i3], y3 = sy[i3];

        // sflp0 = bit15 of h -> sign-bit XOR; sflp1 = bit13 of h -> sign-bit XOR.
        f32x4 oA, oB;
        oA.x = __uint_as_float(__float_as_uint(x0) ^ ((h0 & 0x8000u) << 16));
        oA.y = __uint_as_float(__float_as_uint(y0) ^ ((h0 & 0x2000u) << 18));
        oA.z = __uint_as_float(__float_as_uint(x1) ^ ((h1 & 0x8000u) << 16));
        oA.w = __uint_as_float(__float_as_uint(y1) ^ ((h1 & 0x2000u) << 18));
        oB.x = __uint_as_float(__float_as_uint(x2) ^ ((h2 & 0x8000u) << 16));
        oB.y = __uint_as_float(__float_as_uint(y2) ^ ((h2 & 0x2000u) << 18));
        oB.z = __uint_as_float(__float_as_uint(x3) ^ ((h3 & 0x8000u) << 16));
        oB.w = __uint_as_float(__float_as_uint(y3) ^ ((h3 & 0x2000u) << 18));

        __builtin_nontemporal_store(oA, &out[2 * i]);
        __builtin_nontemporal_store(oB, &out[2 * i + 1]);
    }
}

extern "C" void kernel_launch(void* const* d_in, const int* in_sizes, int n_in,
                              void* d_out, int out_size, void* d_ws, size_t ws_size,
                              hipStream_t stream) {
    const float2* tlut = (const float2*)d_in[0];    // [1024,2] fp32
    const u32x4*  enc  = (const u32x4*)d_in[1];     // [16384,2048] int32, quad-packed
    f32x4*        out  = (f32x4*)d_out;             // [16384,2048,2] fp32 as float4

    const int n_codes = in_sizes[1];                // 16384*2048 = 33,554,432
    const int n4 = n_codes / 4;                     // 8,388,608 quads

    trellis_dequant_kernel<<<GRID, BLOCK, 0, stream>>>(tlut, enc, out, n4);
}

// Round 2
// 356.572 us; speedup vs baseline: 1.0686x; 1.0686x over previous
//
#include <hip/hip_runtime.h>
#include <stdint.h>

// TrellisQuantizer: out[i,j,:] = tlut[(h>>5)&1023] ^ sign(h bits 15/13), h=(e+1)*e
// Memory-bound: 134 MB read (encoded int32) + 268 MB write (fp32 out)
// -> ~64-73 us floor at 5.5-6.5 TB/s mixed-stream achievable.
//
// v3 = v1's access pattern (measured 358 us harness) + split-channel LDS LUT.
//  * v2 post-mortem: storing oA@out[2i] / oB@out[2i+1] made every store
//    instruction stride-32B -> each 64B line half-written by two different
//    instructions -> 2x L2 write transactions on the 268 MB write stream.
//    +23 us regression. REVERTED: one contiguous f32x4 store per lane.
//  * Kept from v2: split LUT. float2[1024] puts entry e at bank-pair
//    (2e)%32 -> random gathers land on only 16 start positions (~4-8-way).
//    Split float sx[]/sy[] puts entry e at bank e%32 -> 64 random lanes
//    over all 32 banks, baseline 2-way aliasing is free (m136).

constexpr int TLUT_ENTRIES = 1024;   // 2^10 entries (8 KiB, LDS-resident)
constexpr int BLOCK = 256;

typedef float f32x4 __attribute__((ext_vector_type(4)));

__global__ __launch_bounds__(BLOCK) void trellis_dequant_kernel(
    const float2*   __restrict__ tlut,   // [1024] float2
    const uint64_t* __restrict__ enc,    // encoded viewed as packed pairs of int32
    f32x4*          __restrict__ out,    // one float4 per code pair
    int n2)                              // number of uint64 (code-pair) elements
{
    __shared__ float sx[TLUT_ENTRIES];
    __shared__ float sy[TLUT_ENTRIES];
    for (int j = threadIdx.x; j < TLUT_ENTRIES; j += BLOCK) {
        float2 t = tlut[j];
        sx[j] = t.x;
        sy[j] = t.y;
    }
    __syncthreads();

    const int stride = gridDim.x * BLOCK;
    int i = blockIdx.x * BLOCK + threadIdx.x;
    #pragma unroll 2
    for (; i < n2; i += stride) {
        // Streamed once, never re-read -> nontemporal, don't occupy L2.
        uint64_t e2 = __builtin_nontemporal_load(&enc[i]);
        uint32_t e0 = (uint32_t)e2;
        uint32_t e1 = (uint32_t)(e2 >> 32);
        uint32_t h0 = (e0 + 1u) * e0;
        uint32_t h1 = (e1 + 1u) * e1;

        uint32_t i0 = (h0 >> 5) & 1023u;
        uint32_t i1 = (h1 >> 5) & 1023u;

        float x0 = sx[i0], y0 = sy[i0];
        float x1 = sx[i1], y1 = sy[i1];

        // sflp0 = bit15 of h -> sign-bit XOR; sflp1 = bit13 of h -> sign-bit XOR.
        f32x4 o;
        o.x = __uint_as_float(__float_as_uint(x0) ^ ((h0 & 0x8000u) << 16));
        o.y = __uint_as_float(__float_as_uint(y0) ^ ((h0 & 0x2000u) << 18));
        o.z = __uint_as_float(__float_as_uint(x1) ^ ((h1 & 0x8000u) << 16));
        o.w = __uint_as_float(__float_as_uint(y1) ^ ((h1 & 0x2000u) << 18));
        __builtin_nontemporal_store(o, &out[i]);
    }
}

extern "C" void kernel_launch(void* const* d_in, const int* in_sizes, int n_in,
                              void* d_out, int out_size, void* d_ws, size_t ws_size,
                              hipStream_t stream) {
    const float2*   tlut = (const float2*)d_in[0];   // [1024,2] fp32
    const uint64_t* enc  = (const uint64_t*)d_in[1]; // [16384,2048] int32, pair-packed
    f32x4*          out  = (f32x4*)d_out;            // [16384,2048,2] fp32 as float4

    const int n_codes = in_sizes[1];                 // 16384*2048 = 33,554,432
    const int n2 = n_codes / 2;                      // 16,777,216 pairs

    const int blocks = 8192;                         // 2M threads -> exactly 8 iters each
    trellis_dequant_kernel<<<blocks, BLOCK, 0, stream>>>(tlut, enc, out, n2);
}